// Round 1
// baseline (295.245 us; speedup 1.0000x reference)
//
#include <hip/hip_runtime.h>

// ---------------------------------------------------------------------------
// SelfAttention (B=8, N=2048, D=U=512), no 1/sqrt(d) scaling.
// Pipeline: X->fp16, W->Wt fp16; QKV = gemm_bt(X, Wt)+b; Vt = transpose(V);
// S = gemm_bt(Q, K) fp32; P = softmax_rows(S) written in-place as fp16;
// O = gemm_bt(P, Vt) -> d_out fp32.
// GEMM core: m97 structure — 128x128 tile, BK=32, 4 waves (2x2), 4x4 frags of
// v_mfma_f32_16x16x32_f16 per wave, global_load_lds width-16 staging.
// ---------------------------------------------------------------------------

typedef _Float16 f16;
typedef _Float16 f16x4 __attribute__((ext_vector_type(4)));
typedef _Float16 f16x8 __attribute__((ext_vector_type(8)));
typedef float f32x4 __attribute__((ext_vector_type(4)));

#define NB 8
#define NS 2048
#define DD 512
#define UU 512

// async global->LDS, 16B per lane; LDS dest is wave-uniform base + lane*16B
__device__ __forceinline__ void stage16(const f16* g, f16* lds_uniform) {
    __builtin_amdgcn_global_load_lds(
        (const __attribute__((address_space(1))) void*)g,
        (__attribute__((address_space(3))) void*)lds_uniform,
        16, 0, 0);
}

// ---------------- prep kernels ----------------

__global__ __launch_bounds__(256) void cvt_x(const float* __restrict__ x,
                                             f16* __restrict__ y, int n) {
    int i = (blockIdx.x * 256 + threadIdx.x) * 4;
    if (i < n) {
        float4 v = *(const float4*)(x + i);
        f16x4 o;
        o[0] = (f16)v.x; o[1] = (f16)v.y; o[2] = (f16)v.z; o[3] = (f16)v.w;
        *(f16x4*)(y + i) = o;
    }
}

__global__ __launch_bounds__(256) void prep_bias(const float* __restrict__ bq,
                                                 const float* __restrict__ bk,
                                                 const float* __restrict__ bv,
                                                 float* __restrict__ out) {
    int i = blockIdx.x * 256 + threadIdx.x;
    if (i < 512) out[i] = bq[i];
    else if (i < 1024) out[i] = bk[i - 512];
    else if (i < 1536) out[i] = bv[i - 1024];
}

// W [D][U] fp32 -> Wt [U][D] fp16 (z selects q/k/v)
__global__ __launch_bounds__(256) void transpose_w(const float* __restrict__ Wq,
                                                   const float* __restrict__ Wk,
                                                   const float* __restrict__ Wv,
                                                   f16* __restrict__ Wt) {
    __shared__ float t[32][33];
    const float* W = (blockIdx.z == 0) ? Wq : (blockIdx.z == 1 ? Wk : Wv);
    f16* out = Wt + (size_t)blockIdx.z * DD * UU;
    int u0 = blockIdx.x * 32, d0 = blockIdx.y * 32;
    int tx = threadIdx.x, ty = threadIdx.y;
#pragma unroll
    for (int r = 0; r < 4; r++)
        t[ty + 8 * r][tx] = W[(size_t)(d0 + ty + 8 * r) * UU + u0 + tx];
    __syncthreads();
#pragma unroll
    for (int r = 0; r < 4; r++)
        out[(size_t)(u0 + ty + 8 * r) * DD + d0 + tx] = (f16)t[tx][ty + 8 * r];
}

// V [b][N][U] f16 -> Vt [b][U][N] f16
__global__ __launch_bounds__(256) void transpose_v(const f16* __restrict__ V,
                                                   f16* __restrict__ Vt) {
    __shared__ f16 t[32][33];
    int b = blockIdx.z;
    const f16* v = V + (size_t)b * NS * UU;
    f16* o = Vt + (size_t)b * UU * NS;
    int u0 = blockIdx.x * 32, n0 = blockIdx.y * 32;
    int tx = threadIdx.x, ty = threadIdx.y;
#pragma unroll
    for (int r = 0; r < 4; r++)
        t[ty + 8 * r][tx] = v[(size_t)(n0 + ty + 8 * r) * UU + u0 + tx];
    __syncthreads();
#pragma unroll
    for (int r = 0; r < 4; r++)
        o[(size_t)(u0 + ty + 8 * r) * NS + n0 + tx] = t[tx][ty + 8 * r];
}

// ---------------- GEMM: C[m][n] = sum_k A[m][k] * Bt[n][k]  (+bias) ----------
// grid: (M/128, N/128, z); block 256 = 4 waves in 2x2; per-wave 64x64 out.
template <bool BIAS, bool OUTF16>
__global__ __launch_bounds__(256) void gemm_bt(
    const f16* __restrict__ A, long sAz, int lda,
    const f16* __restrict__ Bt, long sBz, int ldb,
    const float* __restrict__ bias,      // [z][512] when BIAS
    void* __restrict__ Cv, long sCz, int ldc,
    int K) {
    __shared__ __align__(16) f16 As[128 * 32];
    __shared__ __align__(16) f16 Bs[128 * 32];

    const int tid = threadIdx.x;
    const int wid = tid >> 6;
    const int lane = tid & 63;
    const int z = blockIdx.z;
    const int m0 = blockIdx.x * 128;
    const int n0 = blockIdx.y * 128;

    const f16* Az = A + (size_t)z * sAz;
    const f16* Bz = Bt + (size_t)z * sBz;

    // staging: wave w covers rows [w*32, w*32+32) via two 16-row wave-loads
    const int lrow = wid * 32 + (lane >> 2);     // first call's row
    const int gcol = (lane & 3) * 8;
    const f16* gA = Az + (size_t)(m0 + lrow) * lda + gcol;
    const f16* gA2 = gA + (size_t)16 * lda;
    const f16* gB = Bz + (size_t)(n0 + lrow) * ldb + gcol;
    const f16* gB2 = gB + (size_t)16 * ldb;
    f16* ldsA = &As[(wid * 32) * 32];
    f16* ldsA2 = &As[(wid * 32 + 16) * 32];
    f16* ldsB = &Bs[(wid * 32) * 32];
    f16* ldsB2 = &Bs[(wid * 32 + 16) * 32];

    // fragment read bases
    const int wr = wid >> 1, wc = wid & 1;
    const int frow = lane & 15;
    const int kofs = (lane >> 4) * 8;
    const f16* fA = &As[(wr * 64 + frow) * 32 + kofs];
    const f16* fB = &Bs[(wc * 64 + frow) * 32 + kofs];

    f32x4 acc[4][4] = {};

    for (int kt = 0; kt < K; kt += 32) {
        stage16(gA, ldsA);
        stage16(gA2, ldsA2);
        stage16(gB, ldsB);
        stage16(gB2, ldsB2);
        gA += 32; gA2 += 32; gB += 32; gB2 += 32;
        __syncthreads();   // drains vmcnt(0): LDS tiles complete

        f16x8 af[4], bf[4];
#pragma unroll
        for (int i = 0; i < 4; i++) af[i] = *(const f16x8*)(fA + i * 16 * 32);
#pragma unroll
        for (int i = 0; i < 4; i++) bf[i] = *(const f16x8*)(fB + i * 16 * 32);
#pragma unroll
        for (int mi = 0; mi < 4; mi++)
#pragma unroll
            for (int ni = 0; ni < 4; ni++)
                acc[mi][ni] = __builtin_amdgcn_mfma_f32_16x16x32_f16(
                    af[mi], bf[ni], acc[mi][ni], 0, 0, 0);
        __syncthreads();   // before next iter overwrites LDS
    }

    // epilogue: C/D layout col=lane&15, row=(lane>>4)*4+reg  [m89-verified]
    const int crow0 = m0 + wr * 64 + ((lane >> 4) << 2);
    const int ccol0 = n0 + wc * 64 + (lane & 15);

    if (OUTF16) {
        f16* C = (f16*)Cv + (size_t)z * sCz;
#pragma unroll
        for (int mi = 0; mi < 4; mi++)
#pragma unroll
            for (int ni = 0; ni < 4; ni++) {
                float bv = BIAS ? bias[z * 512 + ccol0 + ni * 16] : 0.0f;
#pragma unroll
                for (int r = 0; r < 4; r++)
                    C[(size_t)(crow0 + mi * 16 + r) * ldc + ccol0 + ni * 16] =
                        (f16)(acc[mi][ni][r] + bv);
            }
    } else {
        float* C = (float*)Cv + (size_t)z * sCz;
#pragma unroll
        for (int mi = 0; mi < 4; mi++)
#pragma unroll
            for (int ni = 0; ni < 4; ni++)
#pragma unroll
                for (int r = 0; r < 4; r++)
                    C[(size_t)(crow0 + mi * 16 + r) * ldc + ccol0 + ni * 16] =
                        acc[mi][ni][r];
    }
}

// ---------------- softmax: one block per row of S (2048 fp32) ---------------
// writes P (f16, 2048 elems) in-place at the row's own base -> lda_P = 4096
__global__ __launch_bounds__(256) void softmax_rows(float* __restrict__ S) {
    float* p = S + (size_t)blockIdx.x * 2048;
    const int t = threadIdx.x;
    const int lane = t & 63, wid = t >> 6;

    float4 v0 = ((const float4*)p)[2 * t];
    float4 v1 = ((const float4*)p)[2 * t + 1];
    float e[8] = {v0.x, v0.y, v0.z, v0.w, v1.x, v1.y, v1.z, v1.w};

    float m = e[0];
#pragma unroll
    for (int j = 1; j < 8; j++) m = fmaxf(m, e[j]);
#pragma unroll
    for (int o = 32; o; o >>= 1) m = fmaxf(m, __shfl_down(m, o, 64));

    __shared__ float redm[4], reds[4];
    if (lane == 0) redm[wid] = m;
    __syncthreads();                       // also drains the global reads
    m = fmaxf(fmaxf(redm[0], redm[1]), fmaxf(redm[2], redm[3]));

    float s = 0.0f;
#pragma unroll
    for (int j = 0; j < 8; j++) { e[j] = __expf(e[j] - m); s += e[j]; }
#pragma unroll
    for (int o = 32; o; o >>= 1) s += __shfl_down(s, o, 64);
    if (lane == 0) reds[wid] = s;
    __syncthreads();
    s = reds[0] + reds[1] + reds[2] + reds[3];
    float inv = 1.0f / s;

    f16* q = (f16*)p;
    f16x8 o8;
#pragma unroll
    for (int j = 0; j < 8; j++) o8[j] = (f16)(e[j] * inv);
    *(f16x8*)(q + 8 * t) = o8;             // safe: all reads drained at barrier
}

// ---------------- launcher ----------------

extern "C" void kernel_launch(void* const* d_in, const int* in_sizes, int n_in,
                              void* d_out, int out_size, void* d_ws, size_t ws_size,
                              hipStream_t stream) {
    const float* X  = (const float*)d_in[0];
    const float* Wq = (const float*)d_in[1];
    const float* bq = (const float*)d_in[2];
    const float* Wk = (const float*)d_in[3];
    const float* bk = (const float*)d_in[4];
    const float* Wv = (const float*)d_in[5];
    const float* bv = (const float*)d_in[6];
    float* out = (float*)d_out;
    char* ws = (char*)d_ws;

    // workspace layout (peak 192 MiB):
    //  [0 .. 134,217,728)  S fp32 [8][2048][2048]  (aliases X16/Wt/biases,
    //                       which are dead once projections complete)
    //    [0 .. 16,777,216)        X16 f16 [16384][512]
    //    [16,777,216 .. 18,350,080) Wt f16 [3][512][512]
    //    [18,350,080 .. 18,356,224) biases fp32 [3][512]
    //  [134,217,728 .. 184,549,376) QKV f16 [3][16384][512]
    //  [184,549,376 .. 201,326,592) Vt f16 [8][512][2048]
    f16*   X16    = (f16*)ws;
    f16*   Wt     = (f16*)(ws + 16777216);
    float* biases = (float*)(ws + 18350080);
    float* S      = (float*)ws;
    f16*   QKV    = (f16*)(ws + 134217728);
    f16*   Vt     = (f16*)(ws + 184549376);

    const long QKVz = (long)16384 * 512;       // 8,388,608 elems per q/k/v

    cvt_x<<<8192, 256, 0, stream>>>(X, X16, 16384 * 512);
    transpose_w<<<dim3(16, 16, 3), dim3(32, 8), 0, stream>>>(Wq, Wk, Wv, Wt);
    prep_bias<<<6, 256, 0, stream>>>(bq, bk, bv, biases);

    // QKV projections: M=16384, N=512, K=512, z in {q,k,v}
    gemm_bt<true, true><<<dim3(128, 4, 3), 256, 0, stream>>>(
        X16, 0L, 512, Wt, (long)512 * 512, 512, biases,
        QKV, QKVz, 512, 512);

    transpose_v<<<dim3(16, 64, 8), dim3(32, 8), 0, stream>>>(QKV + 2 * QKVz, Vt);

    // S = Q K^T : per batch M=N=2048, K=512
    gemm_bt<false, false><<<dim3(16, 16, 8), 256, 0, stream>>>(
        QKV, (long)2048 * 512, 512,
        QKV + QKVz, (long)2048 * 512, 512, nullptr,
        S, (long)2048 * 2048, 2048, 512);

    softmax_rows<<<16384, 256, 0, stream>>>(S);

    // O = P V : per batch M=2048, N=512, K=2048; P rows strided 4096 f16
    gemm_bt<false, false><<<dim3(16, 4, 8), 256, 0, stream>>>(
        (const f16*)S, (long)2048 * 4096, 4096,
        Vt, (long)512 * 2048, 2048, nullptr,
        out, (long)2048 * 512, 512, 2048);
}

// Round 2
// 290.334 us; speedup vs baseline: 1.0169x; 1.0169x over previous
//
#include <hip/hip_runtime.h>

// ---------------------------------------------------------------------------
// SelfAttention (B=8, N=2048, D=U=512), no 1/sqrt(d) scaling.
// Pipeline: X->fp16, W->Wt fp16; Q,K = gemm_bt(X, Wt)+b; Vt = gemm_bt(Wvt, X)+b(row);
// S = gemm_bt(Q, K) fp32; P = softmax_rows(S) in-place f16; O = gemm_bt(P, Vt).
// GEMM core: m97 structure + XOR bank-swizzle of 16B chunks in LDS rows
// (slot = chunk ^ ((row>>1)&3)) — staging side implements the swizzle via the
// per-lane global column, since global_load_lds dest is base + lane*16.
// ---------------------------------------------------------------------------

typedef _Float16 f16;
typedef _Float16 f16x4 __attribute__((ext_vector_type(4)));
typedef _Float16 f16x8 __attribute__((ext_vector_type(8)));
typedef float f32x4 __attribute__((ext_vector_type(4)));

#define NB 8
#define NS 2048
#define DD 512
#define UU 512

__device__ __forceinline__ void stage16(const f16* g, f16* lds_uniform) {
    __builtin_amdgcn_global_load_lds(
        (const __attribute__((address_space(1))) void*)g,
        (__attribute__((address_space(3))) void*)lds_uniform,
        16, 0, 0);
}

// ---------------- prep kernels ----------------

__global__ __launch_bounds__(256) void cvt_x(const float* __restrict__ x,
                                             f16* __restrict__ y, int n) {
    int i = (blockIdx.x * 256 + threadIdx.x) * 4;
    if (i < n) {
        float4 v = *(const float4*)(x + i);
        f16x4 o;
        o[0] = (f16)v.x; o[1] = (f16)v.y; o[2] = (f16)v.z; o[3] = (f16)v.w;
        *(f16x4*)(y + i) = o;
    }
}

__global__ __launch_bounds__(256) void prep_bias(const float* __restrict__ bq,
                                                 const float* __restrict__ bk,
                                                 const float* __restrict__ bv,
                                                 float* __restrict__ out) {
    int i = blockIdx.x * 256 + threadIdx.x;
    if (i < 512) out[i] = bq[i];
    else if (i < 1024) out[i] = bk[i - 512];
    else if (i < 1536) out[i] = bv[i - 1024];
}

// W [D][U] fp32 -> Wt [U][D] fp16 (z selects q/k/v)
__global__ __launch_bounds__(256) void transpose_w(const float* __restrict__ Wq,
                                                   const float* __restrict__ Wk,
                                                   const float* __restrict__ Wv,
                                                   f16* __restrict__ Wt) {
    __shared__ float t[32][33];
    const float* W = (blockIdx.z == 0) ? Wq : (blockIdx.z == 1 ? Wk : Wv);
    f16* out = Wt + (size_t)blockIdx.z * DD * UU;
    int u0 = blockIdx.x * 32, d0 = blockIdx.y * 32;
    int tx = threadIdx.x, ty = threadIdx.y;
#pragma unroll
    for (int r = 0; r < 4; r++)
        t[ty + 8 * r][tx] = W[(size_t)(d0 + ty + 8 * r) * UU + u0 + tx];
    __syncthreads();
#pragma unroll
    for (int r = 0; r < 4; r++)
        out[(size_t)(u0 + ty + 8 * r) * DD + d0 + tx] = (f16)t[tx][ty + 8 * r];
}

// ---------------- GEMM: C[m][n] = sum_k A[m][k] * Bt[n][k]  (+bias) ----------
// grid: (M/128, N/128, z); block 256 = 4 waves in 2x2; per-wave 64x64 out.
// BIASMODE: 0 none, 1 column bias (bias[z*512+col]), 2 row bias (bias[row])
template <int BIASMODE, bool OUTF16>
__global__ __launch_bounds__(256) void gemm_bt(
    const f16* __restrict__ A, long sAz, int lda,
    const f16* __restrict__ Bt, long sBz, int ldb,
    const float* __restrict__ bias,
    void* __restrict__ Cv, long sCz, int ldc,
    int K) {
    __shared__ __align__(16) f16 As[128 * 32];
    __shared__ __align__(16) f16 Bs[128 * 32];

    const int tid = threadIdx.x;
    const int wid = tid >> 6;
    const int lane = tid & 63;
    const int z = blockIdx.z;
    const int m0 = blockIdx.x * 128;
    const int n0 = blockIdx.y * 128;

    const f16* Az = A + (size_t)z * sAz;
    const f16* Bz = Bt + (size_t)z * sBz;

    // staging: wave w covers rows [w*32, w*32+32) via two 16-row wave-loads.
    // XOR swizzle: LDS slot (lane&3) of row (lane>>2) receives global chunk
    // (lane&3) ^ ((row>>1)&3) = (lane&3) ^ ((lane>>3)&3).
    const int lrow = wid * 32 + (lane >> 2);
    const int gcol = (((lane & 3) ^ ((lane >> 3) & 3)) * 8);
    const f16* gA = Az + (size_t)(m0 + lrow) * lda + gcol;
    const f16* gA2 = gA + (size_t)16 * lda;
    const f16* gB = Bz + (size_t)(n0 + lrow) * ldb + gcol;
    const f16* gB2 = gB + (size_t)16 * ldb;
    f16* ldsA = &As[(wid * 32) * 32];
    f16* ldsA2 = &As[(wid * 32 + 16) * 32];
    f16* ldsB = &Bs[(wid * 32) * 32];
    f16* ldsB2 = &Bs[(wid * 32 + 16) * 32];

    // fragment read bases: global chunk (lane>>4) of row frow lives at
    // LDS slot (lane>>4) ^ ((frow>>1)&3). Row+16 doesn't change the swizzle.
    const int wr = wid >> 1, wc = wid & 1;
    const int frow = lane & 15;
    const int fslot = (lane >> 4) ^ ((frow >> 1) & 3);
    const f16* fA = &As[(wr * 64 + frow) * 32 + fslot * 8];
    const f16* fB = &Bs[(wc * 64 + frow) * 32 + fslot * 8];

    f32x4 acc[4][4] = {};

    for (int kt = 0; kt < K; kt += 32) {
        stage16(gA, ldsA);
        stage16(gA2, ldsA2);
        stage16(gB, ldsB);
        stage16(gB2, ldsB2);
        gA += 32; gA2 += 32; gB += 32; gB2 += 32;
        __syncthreads();

        f16x8 af[4], bf[4];
#pragma unroll
        for (int i = 0; i < 4; i++) af[i] = *(const f16x8*)(fA + i * 16 * 32);
#pragma unroll
        for (int i = 0; i < 4; i++) bf[i] = *(const f16x8*)(fB + i * 16 * 32);
#pragma unroll
        for (int mi = 0; mi < 4; mi++)
#pragma unroll
            for (int ni = 0; ni < 4; ni++)
                acc[mi][ni] = __builtin_amdgcn_mfma_f32_16x16x32_f16(
                    af[mi], bf[ni], acc[mi][ni], 0, 0, 0);
        __syncthreads();
    }

    // epilogue: C/D layout col=lane&15, row=(lane>>4)*4+reg  [m89-verified]
    const int crow0 = m0 + wr * 64 + ((lane >> 4) << 2);
    const int ccol0 = n0 + wc * 64 + (lane & 15);

    if (OUTF16) {
        f16* C = (f16*)Cv + (size_t)z * sCz;
#pragma unroll
        for (int mi = 0; mi < 4; mi++)
#pragma unroll
            for (int ni = 0; ni < 4; ni++) {
                float cb = (BIASMODE == 1) ? bias[z * 512 + ccol0 + ni * 16] : 0.0f;
#pragma unroll
                for (int r = 0; r < 4; r++) {
                    float rb = (BIASMODE == 2) ? bias[crow0 + mi * 16 + r] : cb;
                    C[(size_t)(crow0 + mi * 16 + r) * ldc + ccol0 + ni * 16] =
                        (f16)(acc[mi][ni][r] + rb);
                }
            }
    } else {
        float* C = (float*)Cv + (size_t)z * sCz;
#pragma unroll
        for (int mi = 0; mi < 4; mi++)
#pragma unroll
            for (int ni = 0; ni < 4; ni++)
#pragma unroll
                for (int r = 0; r < 4; r++)
                    C[(size_t)(crow0 + mi * 16 + r) * ldc + ccol0 + ni * 16] =
                        acc[mi][ni][r];
    }
}

// ---------------- softmax: one block per row of S (2048 fp32) ---------------
__global__ __launch_bounds__(256) void softmax_rows(float* __restrict__ S) {
    float* p = S + (size_t)blockIdx.x * 2048;
    const int t = threadIdx.x;
    const int lane = t & 63, wid = t >> 6;

    float4 v0 = ((const float4*)p)[2 * t];
    float4 v1 = ((const float4*)p)[2 * t + 1];
    float e[8] = {v0.x, v0.y, v0.z, v0.w, v1.x, v1.y, v1.z, v1.w};

    float m = e[0];
#pragma unroll
    for (int j = 1; j < 8; j++) m = fmaxf(m, e[j]);
#pragma unroll
    for (int o = 32; o; o >>= 1) m = fmaxf(m, __shfl_down(m, o, 64));

    __shared__ float redm[4], reds[4];
    if (lane == 0) redm[wid] = m;
    __syncthreads();
    m = fmaxf(fmaxf(redm[0], redm[1]), fmaxf(redm[2], redm[3]));

    float s = 0.0f;
#pragma unroll
    for (int j = 0; j < 8; j++) { e[j] = __expf(e[j] - m); s += e[j]; }
#pragma unroll
    for (int o = 32; o; o >>= 1) s += __shfl_down(s, o, 64);
    if (lane == 0) reds[wid] = s;
    __syncthreads();
    s = reds[0] + reds[1] + reds[2] + reds[3];
    float inv = 1.0f / s;

    f16* q = (f16*)p;
    f16x8 o8;
#pragma unroll
    for (int j = 0; j < 8; j++) o8[j] = (f16)(e[j] * inv);
    *(f16x8*)(q + 8 * t) = o8;
}

// ---------------- launcher ----------------

extern "C" void kernel_launch(void* const* d_in, const int* in_sizes, int n_in,
                              void* d_out, int out_size, void* d_ws, size_t ws_size,
                              hipStream_t stream) {
    const float* X  = (const float*)d_in[0];
    const float* Wq = (const float*)d_in[1];
    const float* bq = (const float*)d_in[2];
    const float* Wk = (const float*)d_in[3];
    const float* bk = (const float*)d_in[4];
    const float* Wv = (const float*)d_in[5];
    const float* bv = (const float*)d_in[6];
    float* out = (float*)d_out;
    char* ws = (char*)d_ws;

    // workspace layout (peak 192 MiB):
    //  [0 .. 134,217,728)  S fp32 [8][2048][2048]  (aliases X16/Wt/biases,
    //                       which are dead once projections complete)
    //    [0 .. 16,777,216)          X16 f16 [16384][512]
    //    [16,777,216 .. 18,350,080) Wt f16 [3][512][512] (Wqt, Wkt, Wvt)
    //    [18,350,080 .. 18,356,224) biases fp32 [3][512]
    //  [134,217,728 .. 184,549,376) QK f16 [2][16384][512]
    //  [184,549,376 .. 201,326,592) Vt f16 [8][512][2048]
    f16*   X16    = (f16*)ws;
    f16*   Wt     = (f16*)(ws + 16777216);
    float* biases = (float*)(ws + 18350080);
    float* S      = (float*)ws;
    f16*   QK     = (f16*)(ws + 134217728);
    f16*   Vt     = (f16*)(ws + 184549376);

    const long QKz = (long)16384 * 512;        // 8,388,608 elems per q/k

    cvt_x<<<8192, 256, 0, stream>>>(X, X16, 16384 * 512);
    transpose_w<<<dim3(16, 16, 3), dim3(32, 8), 0, stream>>>(Wq, Wk, Wv, Wt);
    prep_bias<<<6, 256, 0, stream>>>(bq, bk, bv, biases);

    // Q,K projections: M=16384, N=512, K=512, z in {q,k}; column bias
    gemm_bt<1, true><<<dim3(128, 4, 2), 256, 0, stream>>>(
        X16, 0L, 512, Wt, (long)512 * 512, 512, biases,
        QK, QKz, 512, 512);

    // Vt projection: Vt_b[u][n] = sum_d Wvt[u][d] * X_b[n][d] + bv[u]
    // M=512 (u), N=2048 (n), K=512, z = batch; row bias (bv at biases+1024)
    gemm_bt<2, true><<<dim3(4, 16, 8), 256, 0, stream>>>(
        Wt + (size_t)2 * 512 * 512, 0L, 512,
        X16, (long)2048 * 512, 512, biases + 1024,
        Vt, (long)512 * 2048, 2048, 512);

    // S = Q K^T : per batch M=N=2048, K=512
    gemm_bt<0, false><<<dim3(16, 16, 8), 256, 0, stream>>>(
        QK, (long)2048 * 512, 512,
        QK + QKz, (long)2048 * 512, 512, nullptr,
        S, (long)2048 * 2048, 2048, 512);

    softmax_rows<<<16384, 256, 0, stream>>>(S);

    // O = P V : per batch M=2048, N=512, K=2048; P rows strided 4096 f16
    gemm_bt<0, false><<<dim3(16, 4, 8), 256, 0, stream>>>(
        (const f16*)S, (long)2048 * 4096, 4096,
        Vt, (long)512 * 2048, 2048, nullptr,
        out, (long)2048 * 512, 512, 2048);
}

// Round 3
// 261.811 us; speedup vs baseline: 1.1277x; 1.1089x over previous
//
#include <hip/hip_runtime.h>

// ---------------------------------------------------------------------------
// SelfAttention (B=8, N=2048, D=U=512), no 1/sqrt(d) scaling.
// prep_fused: X->f16, W->Wt f16, bias gather        (1 launch)
// proj_fused: Q,K = X*Wt+b ; Vt = Wvt*X^T+bv        (1 launch, 1536 blocks)
// S = Q K^T fp32; softmax rows -> P f16 in-place; O = P Vt -> out fp32.
// GEMM core: 128x128 tile, BK=64 (2 k-chunks per barrier pair -> half the
// vmcnt(0) barrier drains of BK=32), global_load_lds width-16 staging,
// XOR bank swizzle slot = chunk ^ (row&7) on 128B LDS rows.
// ---------------------------------------------------------------------------

typedef _Float16 f16;
typedef _Float16 f16x4 __attribute__((ext_vector_type(4)));
typedef _Float16 f16x8 __attribute__((ext_vector_type(8)));
typedef float f32x4 __attribute__((ext_vector_type(4)));

__device__ __forceinline__ void stage16(const f16* g, f16* lds_uniform) {
    __builtin_amdgcn_global_load_lds(
        (const __attribute__((address_space(1))) void*)g,
        (__attribute__((address_space(3))) void*)lds_uniform,
        16, 0, 0);
}

// ---------------- prep (fused): cvt_x | transpose_w | bias gather -----------
__global__ __launch_bounds__(256) void prep_fused(
    const float* __restrict__ X,
    const float* __restrict__ Wq, const float* __restrict__ Wk,
    const float* __restrict__ Wv,
    const float* __restrict__ bq, const float* __restrict__ bk,
    const float* __restrict__ bv,
    f16* __restrict__ X16, f16* __restrict__ Wt, float* __restrict__ biases) {
    __shared__ float t[32][33];
    const int bid = blockIdx.x, tid = threadIdx.x;
    if (bid < 8192) {
        int i = (bid * 256 + tid) * 4;
        float4 v = *(const float4*)(X + i);
        f16x4 o;
        o[0] = (f16)v.x; o[1] = (f16)v.y; o[2] = (f16)v.z; o[3] = (f16)v.w;
        *(f16x4*)(X16 + i) = o;
    } else if (bid < 8960) {
        int id = bid - 8192;
        int z = id >> 8, rem = id & 255;
        int u0 = (rem & 15) * 32, d0 = (rem >> 4) * 32;
        const float* W = (z == 0) ? Wq : (z == 1 ? Wk : Wv);
        f16* outp = Wt + (size_t)z * 262144;
        int tx = tid & 31, ty = tid >> 5;
#pragma unroll
        for (int r = 0; r < 4; r++)
            t[ty + 8 * r][tx] = W[(size_t)(d0 + ty + 8 * r) * 512 + u0 + tx];
        __syncthreads();
#pragma unroll
        for (int r = 0; r < 4; r++)
            outp[(size_t)(u0 + ty + 8 * r) * 512 + d0 + tx] = (f16)t[tx][ty + 8 * r];
    } else {
#pragma unroll
        for (int j = 0; j < 6; j++) {
            int i = j * 256 + tid;
            float v = (i < 512) ? bq[i] : (i < 1024) ? bk[i - 512] : bv[i - 1024];
            biases[i] = v;
        }
    }
}

// ---------------- shared GEMM core: C = A * Bt^T (+bias) --------------------
// 128x128 tile at (m0,n0); BK=64; 4 waves in 2x2, each 64x64 via 4x4 frags of
// v_mfma_f32_16x16x32_f16. LDS rows 64 f16 = 128B = 8 chunks of 16B;
// physical slot of logical chunk c in row r is c ^ (r&7).
__device__ __forceinline__ void gemm_core(
    const f16* __restrict__ A, int lda,
    const f16* __restrict__ Bt, int ldb,
    int m0, int n0, int K,
    int biasmode, const float* __restrict__ bias,   // 0 none, 1 col, 2 row
    void* __restrict__ Cv, int ldc, bool outf16,
    f16* As, f16* Bs) {
    const int tid = threadIdx.x;
    const int wid = tid >> 6, lane = tid & 63;

    // staging: wave w covers rows [w*32, w*32+32) of A and B, 4 calls of
    // 8 rows each. stage16 lane layout: row_local = lane>>3, slot = lane&7;
    // logical chunk = slot ^ (row&7) = (lane&7) ^ ((lane>>3)&7).
    const int schunk = (lane & 7) ^ ((lane >> 3) & 7);
    const f16* gA = A + (size_t)(m0 + wid * 32 + (lane >> 3)) * lda + schunk * 8;
    const f16* gB = Bt + (size_t)(n0 + wid * 32 + (lane >> 3)) * ldb + schunk * 8;
    f16* ldsA = As + (wid * 32) * 64;
    f16* ldsB = Bs + (wid * 32) * 64;

    // fragment bases: A[m=lane&15][k=(lane>>4)*8+j], chunks 0..3 (k<32) and
    // 4..7 (k>=32); slot = chunk ^ (frow&7) (row+16/32/48 keeps frow&7).
    const int wr = wid >> 1, wc = wid & 1;
    const int frow = lane & 15;
    const int f7 = frow & 7;
    const int c_lo = (lane >> 4) ^ f7;
    const int c_hi = ((lane >> 4) | 4) ^ f7;
    const f16* fA_lo = As + (wr * 64 + frow) * 64 + c_lo * 8;
    const f16* fA_hi = As + (wr * 64 + frow) * 64 + c_hi * 8;
    const f16* fB_lo = Bs + (wc * 64 + frow) * 64 + c_lo * 8;
    const f16* fB_hi = Bs + (wc * 64 + frow) * 64 + c_hi * 8;

    f32x4 acc[4][4] = {};

    for (int kt = 0; kt < K; kt += 64) {
#pragma unroll
        for (int j = 0; j < 4; j++)
            stage16(gA + (size_t)(j * 8) * lda, ldsA + (j * 8) * 64);
#pragma unroll
        for (int j = 0; j < 4; j++)
            stage16(gB + (size_t)(j * 8) * ldb, ldsB + (j * 8) * 64);
        gA += 64; gB += 64;
        __syncthreads();

        {
            f16x8 af[4], bf[4];
#pragma unroll
            for (int i = 0; i < 4; i++) af[i] = *(const f16x8*)(fA_lo + i * 16 * 64);
#pragma unroll
            for (int i = 0; i < 4; i++) bf[i] = *(const f16x8*)(fB_lo + i * 16 * 64);
#pragma unroll
            for (int mi = 0; mi < 4; mi++)
#pragma unroll
                for (int ni = 0; ni < 4; ni++)
                    acc[mi][ni] = __builtin_amdgcn_mfma_f32_16x16x32_f16(
                        af[mi], bf[ni], acc[mi][ni], 0, 0, 0);
        }
        {
            f16x8 af[4], bf[4];
#pragma unroll
            for (int i = 0; i < 4; i++) af[i] = *(const f16x8*)(fA_hi + i * 16 * 64);
#pragma unroll
            for (int i = 0; i < 4; i++) bf[i] = *(const f16x8*)(fB_hi + i * 16 * 64);
#pragma unroll
            for (int mi = 0; mi < 4; mi++)
#pragma unroll
                for (int ni = 0; ni < 4; ni++)
                    acc[mi][ni] = __builtin_amdgcn_mfma_f32_16x16x32_f16(
                        af[mi], bf[ni], acc[mi][ni], 0, 0, 0);
        }
        __syncthreads();
    }

    // epilogue: C/D layout col=lane&15, row=(lane>>4)*4+reg  [m89-verified]
    const int crow0 = m0 + wr * 64 + ((lane >> 4) << 2);
    const int ccol0 = n0 + wc * 64 + (lane & 15);

    if (outf16) {
        f16* C = (f16*)Cv;
#pragma unroll
        for (int mi = 0; mi < 4; mi++)
#pragma unroll
            for (int ni = 0; ni < 4; ni++) {
                float cb = (biasmode == 1) ? bias[ccol0 + ni * 16] : 0.0f;
#pragma unroll
                for (int r = 0; r < 4; r++) {
                    float rb = (biasmode == 2) ? bias[crow0 + mi * 16 + r] : cb;
                    C[(size_t)(crow0 + mi * 16 + r) * ldc + ccol0 + ni * 16] =
                        (f16)(acc[mi][ni][r] + rb);
                }
            }
    } else {
        float* C = (float*)Cv;
#pragma unroll
        for (int mi = 0; mi < 4; mi++)
#pragma unroll
            for (int ni = 0; ni < 4; ni++)
#pragma unroll
                for (int r = 0; r < 4; r++)
                    C[(size_t)(crow0 + mi * 16 + r) * ldc + ccol0 + ni * 16] =
                        acc[mi][ni][r];
    }
}

// ---------------- fused projections: Q,K (1024 blocks) + Vt (512 blocks) ----
__global__ __launch_bounds__(256) void proj_fused(
    const f16* __restrict__ X16, const f16* __restrict__ Wt,
    const float* __restrict__ biases,
    f16* __restrict__ QK, f16* __restrict__ Vt) {
    __shared__ __align__(16) f16 As[128 * 64];
    __shared__ __align__(16) f16 Bs[128 * 64];
    const int bid = blockIdx.x;
    if (bid < 1024) {
        // Q/K proj: M=16384, N=512, K=512; z in {0,1}; column bias
        int z = bid >> 9, rem = bid & 511;
        int bx = rem & 127, by = rem >> 7;
        gemm_core(X16, 512, Wt + (size_t)z * 262144, 512,
                  bx * 128, by * 128, 512,
                  1, biases + z * 512,
                  QK + (size_t)z * 8388608, 512, true, As, Bs);
    } else {
        // Vt proj: Vt_b[u][n] = sum_d Wvt[u][d] X_b[n][d] + bv[u]
        // M=512, N=2048, K=512; z=batch; row bias
        int id = bid - 1024;
        int bz = id >> 6, rem = id & 63;
        int bx = rem & 3, by = rem >> 2;
        gemm_core(Wt + (size_t)2 * 262144, 512,
                  X16 + (size_t)bz * 1048576, 512,
                  bx * 128, by * 128, 512,
                  2, biases + 1024,
                  Vt + (size_t)bz * 1048576, 2048, true, As, Bs);
    }
}

// ---------------- batched fp32-out GEMM (S and O) ---------------------------
__global__ __launch_bounds__(256) void gemm_f32(
    const f16* __restrict__ A, long sAz, int lda,
    const f16* __restrict__ Bt, long sBz, int ldb,
    float* __restrict__ C, long sCz, int ldc, int K) {
    __shared__ __align__(16) f16 As[128 * 64];
    __shared__ __align__(16) f16 Bs[128 * 64];
    gemm_core(A + (size_t)blockIdx.z * sAz, lda,
              Bt + (size_t)blockIdx.z * sBz, ldb,
              blockIdx.x * 128, blockIdx.y * 128, K,
              0, nullptr,
              C + (size_t)blockIdx.z * sCz, ldc, false, As, Bs);
}

// ---------------- softmax: one block per row of S (2048 fp32) ---------------
__global__ __launch_bounds__(256) void softmax_rows(float* __restrict__ S) {
    float* p = S + (size_t)blockIdx.x * 2048;
    const int t = threadIdx.x;
    const int lane = t & 63, wid = t >> 6;

    float4 v0 = ((const float4*)p)[2 * t];
    float4 v1 = ((const float4*)p)[2 * t + 1];
    float e[8] = {v0.x, v0.y, v0.z, v0.w, v1.x, v1.y, v1.z, v1.w};

    float m = e[0];
#pragma unroll
    for (int j = 1; j < 8; j++) m = fmaxf(m, e[j]);
#pragma unroll
    for (int o = 32; o; o >>= 1) m = fmaxf(m, __shfl_down(m, o, 64));

    __shared__ float redm[4], reds[4];
    if (lane == 0) redm[wid] = m;
    __syncthreads();
    m = fmaxf(fmaxf(redm[0], redm[1]), fmaxf(redm[2], redm[3]));

    float s = 0.0f;
#pragma unroll
    for (int j = 0; j < 8; j++) { e[j] = __expf(e[j] - m); s += e[j]; }
#pragma unroll
    for (int o = 32; o; o >>= 1) s += __shfl_down(s, o, 64);
    if (lane == 0) reds[wid] = s;
    __syncthreads();
    s = reds[0] + reds[1] + reds[2] + reds[3];
    float inv = 1.0f / s;

    f16* q = (f16*)p;
    f16x8 o8;
#pragma unroll
    for (int j = 0; j < 8; j++) o8[j] = (f16)(e[j] * inv);
    *(f16x8*)(q + 8 * t) = o8;
}

// ---------------- launcher ----------------

extern "C" void kernel_launch(void* const* d_in, const int* in_sizes, int n_in,
                              void* d_out, int out_size, void* d_ws, size_t ws_size,
                              hipStream_t stream) {
    const float* X  = (const float*)d_in[0];
    const float* Wq = (const float*)d_in[1];
    const float* bq = (const float*)d_in[2];
    const float* Wk = (const float*)d_in[3];
    const float* bk = (const float*)d_in[4];
    const float* Wv = (const float*)d_in[5];
    const float* bv = (const float*)d_in[6];
    float* out = (float*)d_out;
    char* ws = (char*)d_ws;

    // workspace layout (peak 192 MiB):
    //  [0 .. 134,217,728)  S fp32 [8][2048][2048]  (aliases X16/Wt/biases)
    //    [0 .. 16,777,216)          X16 f16 [16384][512]
    //    [16,777,216 .. 18,350,080) Wt f16 [3][512][512]
    //    [18,350,080 .. 18,356,224) biases fp32 [3][512]
    //  [134,217,728 .. 184,549,376) QK f16 [2][16384][512]
    //  [184,549,376 .. 201,326,592) Vt f16 [8][512][2048]
    f16*   X16    = (f16*)ws;
    f16*   Wt     = (f16*)(ws + 16777216);
    float* biases = (float*)(ws + 18350080);
    float* S      = (float*)ws;
    f16*   QK     = (f16*)(ws + 134217728);
    f16*   Vt     = (f16*)(ws + 184549376);

    prep_fused<<<8961, 256, 0, stream>>>(X, Wq, Wk, Wv, bq, bk, bv,
                                         X16, Wt, biases);

    proj_fused<<<1536, 256, 0, stream>>>(X16, Wt, biases, QK, Vt);

    // S = Q K^T : per batch M=N=2048, K=512
    gemm_f32<<<dim3(16, 16, 8), 256, 0, stream>>>(
        QK, (long)2048 * 512, 512,
        QK + (size_t)8388608, (long)2048 * 512, 512,
        S, (long)2048 * 2048, 2048, 512);

    softmax_rows<<<16384, 256, 0, stream>>>(S);

    // O = P V : per batch M=2048, N=512, K=2048; P rows strided 4096 f16
    gemm_f32<<<dim3(16, 4, 8), 256, 0, stream>>>(
        (const f16*)S, (long)2048 * 4096, 4096,
        Vt, (long)512 * 2048, 2048,
        out, (long)2048 * 512, 512, 2048);
}